// Round 5
// baseline (19872.624 us; speedup 1.0000x reference)
//
#include <hip/hip_runtime.h>
#include <hip/hip_fp16.h>
#include <math.h>

#define NPTS 2048
#define DIM 32
#define NPAIR 5
#define NT 6
// sweep decomposition: 16 column-groups x 128 cols, 16 row-strips x 128 rows
#define NSTRIP 16
#define NGRP 16
#define GCOLS 128
#define SUBROWS 32   // rows per thread: 128-row strip / 4 substrips

#if __has_builtin(__builtin_amdgcn_exp2f)
__device__ __forceinline__ float exp2_fast(float x) { return __builtin_amdgcn_exp2f(x); }
#else
__device__ __forceinline__ float exp2_fast(float x) { return exp2f(x); }
#endif
#if __has_builtin(__builtin_amdgcn_logf)
__device__ __forceinline__ float log2_fast(float x) { return __builtin_amdgcn_logf(x); }
#else
__device__ __forceinline__ float log2_fast(float x) { return log2f(x); }
#endif

// Online base-2 LSE update, single exp2 per element (branch-free select).
__device__ __forceinline__ void lse_update(float& m, float& s, float u) {
  float mn = fmaxf(m, u);
  float e = exp2_fast(fminf(m, u) - mn);
  bool gt = u > m;
  s = fmaf(s, gt ? e : 1.0f, gt ? 1.0f : e);
  m = mn;
}

// Merge two (m,s) LSE partials.
__device__ __forceinline__ void lse_merge(float& m, float& s, float m2, float s2) {
  float mn = fmaxf(m, m2);
  s = fmaf(s, exp2_fast(m - mn), s2 * exp2_fast(m2 - mn));
  m = mn;
}

__global__ __launch_bounds__(256) void init_kernel(
    const float* __restrict__ x, float* __restrict__ norms,
    float* __restrict__ f, float* __restrict__ g, int* __restrict__ cnt) {
  int idx = blockIdx.x * 256 + threadIdx.x;
  if (idx < NT * NPTS) {
    const float* row = x + (size_t)idx * DIM;
    float d0 = 0.f, d1 = 0.f, d2 = 0.f, d3 = 0.f;
#pragma unroll
    for (int k = 0; k < DIM; k += 4) {
      d0 = fmaf(row[k + 0], row[k + 0], d0);
      d1 = fmaf(row[k + 1], row[k + 1], d1);
      d2 = fmaf(row[k + 2], row[k + 2], d2);
      d3 = fmaf(row[k + 3], row[k + 3], d3);
    }
    norms[idx] = (d0 + d1) + (d2 + d3);
  }
  if (idx < NPAIR * NPTS) { f[idx] = 0.f; g[idx] = 0.f; }
  if (idx < 2 * NPAIR * NGRP) cnt[idx] = 0;
}

// C[p][i][j] = 0.5*(|x_i|^2+|y_j|^2) - x_i.y_j, stored fp16 in BOTH layouts:
// C row-major [p][i][j] and CT transposed [p][j][i].
__global__ __launch_bounds__(256) void cmat_kernel(
    const float* __restrict__ x, const float* __restrict__ norms,
    __half* __restrict__ C, __half* __restrict__ CT) {
  int bid = blockIdx.x;
  int p = bid >> 10;
  int ib = (bid >> 5) & 31;
  int jb = bid & 31;
  const float* xr = x + (size_t)p * NPTS * DIM;
  const float* yr = x + (size_t)(p + 1) * NPTS * DIM;
  __shared__ float xs[64][DIM];
  __shared__ float ys[64][DIM + 1];
  __shared__ __half cc[64][66];   // 64x64 tile, row pad 66 (even, 132B stride)
  int tid = threadIdx.x;
  for (int r = 0; r < 8; ++r) {
    int e = (r << 8) + tid;
    int i = e >> 5, k = e & 31;
    xs[i][k] = xr[(size_t)(ib << 6) * DIM + e];
    ys[i][k] = yr[(size_t)(jb << 6) * DIM + e];
  }
  __syncthreads();
  int jloc = tid & 63, istrip = tid >> 6;
  float nyv = norms[(p + 1) * NPTS + (jb << 6) + jloc];
  for (int ii = 0; ii < 16; ++ii) {
    int i = (istrip << 4) + ii;
    float d0 = 0.f, d1 = 0.f, d2 = 0.f, d3 = 0.f;
#pragma unroll
    for (int k = 0; k < DIM; k += 4) {
      d0 = fmaf(xs[i][k + 0], ys[jloc][k + 0], d0);
      d1 = fmaf(xs[i][k + 1], ys[jloc][k + 1], d1);
      d2 = fmaf(xs[i][k + 2], ys[jloc][k + 2], d2);
      d3 = fmaf(xs[i][k + 3], ys[jloc][k + 3], d3);
    }
    float nxv = norms[p * NPTS + (ib << 6) + i];
    cc[i][jloc] = __float2half_rn(fmaf(0.5f, nxv + nyv, -((d0 + d1) + (d2 + d3))));
  }
  __syncthreads();
  // write C rows (contiguous in j)
  for (int r = 0; r < 8; ++r) {
    int e = (r << 8) + tid;
    int row = e >> 5, h2 = e & 31;
    __half2 v = *(__half2*)&cc[row][2 * h2];
    ((__half2*)(C + ((size_t)p * NPTS + (ib << 6) + row) * NPTS + (jb << 6)))[h2] = v;
  }
  // write CT rows (row = original col j, contiguous in i)
  for (int r = 0; r < 8; ++r) {
    int e = (r << 8) + tid;
    int col = e >> 5, h2 = e & 31;
    __half2 v = __halves2half2(cc[2 * h2][col], cc[2 * h2 + 1][col]);
    ((__half2*)(CT + ((size_t)p * NPTS + (jb << 6) + col) * NPTS + (ib << 6)))[h2] = v;
  }
}

// Generic Sinkhorn half-sweep over matrix M (fp16, [p][row][col], col contiguous):
//   dst[col] = cs * LSE2_row[(src[row] - M[row][col]) * kk] + cb
// grid: NPAIR * NGRP * NSTRIP blocks of 256. Each block does a 128-row strip of a
// 128-col group; last-arriving strip-block (device-atomic ticket) merges partials.
__global__ __launch_bounds__(256) void sweep_kernel(
    const __half2* __restrict__ M, const float* __restrict__ src,
    float* __restrict__ dst, float* __restrict__ pm, float* __restrict__ ps,
    int* __restrict__ cnt, float kk, float cs, float cb) {
  int b = blockIdx.x;
  int p = b >> 8;              // NGRP*NSTRIP = 256 blocks per pair
  int grp = (b >> 4) & (NGRP - 1);
  int strip = b & (NSTRIP - 1);
  int tid = threadIdx.x;
  int cpair = tid & 63;        // handles cols 2*cpair, 2*cpair+1 within group
  int sub = tid >> 6;
  int row0 = strip * 128 + sub * SUBROWS;
  const __half2* Mp = M + ((size_t)p * NPTS + row0) * (NPTS / 2)
                        + grp * (GCOLS / 2) + cpair;
  const float* sp = src + p * NPTS + row0;
  float ma0 = -INFINITY, ma1 = -INFINITY, mb0 = -INFINITY, mb1 = -INFINITY;
  float sa0 = 0.f, sa1 = 0.f, sb0 = 0.f, sb1 = 0.f;
#pragma unroll 4
  for (int ii = 0; ii < SUBROWS; ii += 2) {
    float2 ca = __half22float2(Mp[(size_t)ii * (NPTS / 2)]);
    float2 cb2 = __half22float2(Mp[(size_t)(ii + 1) * (NPTS / 2)]);
    float fa = sp[ii] * kk;
    float fb = sp[ii + 1] * kk;
    lse_update(ma0, sa0, fmaf(-kk, ca.x, fa));
    lse_update(ma1, sa1, fmaf(-kk, ca.y, fa));
    lse_update(mb0, sb0, fmaf(-kk, cb2.x, fb));
    lse_update(mb1, sb1, fmaf(-kk, cb2.y, fb));
  }
  lse_merge(ma0, sa0, mb0, sb0);
  lse_merge(ma1, sa1, mb1, sb1);
  // merge 4 substrips via LDS
  __shared__ float lm[4][GCOLS], lsum[4][GCOLS];
  lm[sub][2 * cpair] = ma0;     lsum[sub][2 * cpair] = sa0;
  lm[sub][2 * cpair + 1] = ma1; lsum[sub][2 * cpair + 1] = sa1;
  __syncthreads();
  int gidx = p * NGRP + grp;
  if (tid < GCOLS) {
    float Mv = lm[0][tid], Sv = lsum[0][tid];
    lse_merge(Mv, Sv, lm[1][tid], lsum[1][tid]);
    lse_merge(Mv, Sv, lm[2][tid], lsum[2][tid]);
    lse_merge(Mv, Sv, lm[3][tid], lsum[3][tid]);
    size_t pidx = ((size_t)gidx * NSTRIP + strip) * GCOLS + tid;
    __hip_atomic_store(&pm[pidx], Mv, __ATOMIC_RELAXED, __HIP_MEMORY_SCOPE_AGENT);
    __hip_atomic_store(&ps[pidx], Sv, __ATOMIC_RELAXED, __HIP_MEMORY_SCOPE_AGENT);
  }
  __threadfence();
  __syncthreads();
  __shared__ int isLast;
  if (tid == 0) isLast = (atomicAdd(&cnt[gidx], 1) == NSTRIP - 1);
  __syncthreads();
  if (!isLast) return;
  __threadfence();
  if (tid < GCOLS) {
    size_t base = (size_t)gidx * NSTRIP * GCOLS + tid;
    float Mv = __hip_atomic_load(&pm[base], __ATOMIC_RELAXED, __HIP_MEMORY_SCOPE_AGENT);
    float Sv = __hip_atomic_load(&ps[base], __ATOMIC_RELAXED, __HIP_MEMORY_SCOPE_AGENT);
#pragma unroll
    for (int s = 1; s < NSTRIP; ++s) {
      float m2 = __hip_atomic_load(&pm[base + (size_t)s * GCOLS], __ATOMIC_RELAXED, __HIP_MEMORY_SCOPE_AGENT);
      float s2 = __hip_atomic_load(&ps[base + (size_t)s * GCOLS], __ATOMIC_RELAXED, __HIP_MEMORY_SCOPE_AGENT);
      lse_merge(Mv, Sv, m2, s2);
    }
    dst[p * NPTS + grp * GCOLS + tid] = fmaf(cs, Mv + log2_fast(Sv), cb);
  }
  if (tid == 0)
    __hip_atomic_store(&cnt[gidx], 0, __ATOMIC_RELAXED, __HIP_MEMORY_SCOPE_AGENT);
}

__global__ __launch_bounds__(256) void out_kernel(
    const float* __restrict__ f, const float* __restrict__ g, float* __restrict__ out) {
  int p = blockIdx.x;
  int tid = threadIdx.x;
  float s = 0.f;
  for (int r = tid; r < NPTS; r += 256) s += f[p * NPTS + r] + g[p * NPTS + r];
  __shared__ float red[256];
  red[tid] = s;
  __syncthreads();
  for (int h = 128; h > 0; h >>= 1) {
    if (tid < h) red[tid] += red[tid + h];
    __syncthreads();
  }
  if (tid == 0) atomicAdd(out, red[0] * (0.05f / (float)NPTS));
}

extern "C" void kernel_launch(void* const* d_in, const int* in_sizes, int n_in,
                              void* d_out, int out_size, void* d_ws, size_t ws_size,
                              hipStream_t stream) {
  const float* x = (const float*)d_in[0];
  float* out = (float*)d_out;
  float* f = (float*)d_ws;
  float* g = f + NPAIR * NPTS;
  float* norms = g + NPAIR * NPTS;
  float* pm = norms + NT * NPTS;
  float* ps = pm + (size_t)NPAIR * NGRP * NSTRIP * GCOLS;
  int* cnt = (int*)(ps + (size_t)NPAIR * NGRP * NSTRIP * GCOLS);
  size_t head = (char*)(cnt + 2 * NPAIR * NGRP) - (char*)d_ws;
  size_t coff = (head + 255) & ~(size_t)255;
  __half* C = (__half*)((char*)d_ws + coff);
  __half* CT = C + (size_t)NPAIR * NPTS * NPTS;

  hipMemsetAsync(d_out, 0, sizeof(float), stream);
  init_kernel<<<(NT * NPTS + 255) / 256, 256, 0, stream>>>(x, norms, f, g, cnt);
  cmat_kernel<<<NPAIR * 1024, 256, 0, stream>>>(x, norms, C, CT);

  const double LN2 = 0.6931471805599453;
  const double LOGN = 7.624618986159398;  // ln(2048)
  const int NBLK = NPAIR * NGRP * NSTRIP; // 1280
  for (int t = 0; t < 80; ++t) {
    double eps = 100.0 * pow(0.95, 2.0 * (double)t);
    if (eps < 0.05) eps = 0.05;
    float kk = (float)(1.0 / (eps * LN2));
    float cs = (float)(-eps * LN2);
    float cb = (float)(eps * LOGN);
    // g_j = cs*LSE2_i[(f_i - C_ij)*kk] + cb   : sweep C (rows=i, cols=j)
    sweep_kernel<<<NBLK, 256, 0, stream>>>((const __half2*)C, f, g, pm, ps,
                                           cnt, kk, cs, cb);
    // f_i = cs*LSE2_j[(g_j - C_ij)*kk] + cb   : sweep CT (rows=j, cols=i)
    sweep_kernel<<<NBLK, 256, 0, stream>>>((const __half2*)CT, g, f, pm, ps,
                                           cnt + NPAIR * NGRP, kk, cs, cb);
  }
  out_kernel<<<NPAIR, 256, 0, stream>>>(f, g, out);
}

// Round 9
// 1949.635 us; speedup vs baseline: 10.1930x; 10.1930x over previous
//
#include <hip/hip_runtime.h>
#include <hip/hip_fp16.h>
#include <math.h>

#define NPTS 2048
#define DIM 32
#define NPAIR 5
#define NT 6
#define NSTRIP 16      // row strips per sweep (cross-dispatch partials)
#define NGRP 16        // col groups per sweep
#define GCOLS 128      // cols per block
#define SROWS 128      // rows per strip (per block)
#define SUBROWS 32     // rows per thread sub-chain (4 subs per block)

#if __has_builtin(__builtin_amdgcn_exp2f)
__device__ __forceinline__ float exp2_fast(float x) { return __builtin_amdgcn_exp2f(x); }
#else
__device__ __forceinline__ float exp2_fast(float x) { return exp2f(x); }
#endif
#if __has_builtin(__builtin_amdgcn_logf)
__device__ __forceinline__ float log2_fast(float x) { return __builtin_amdgcn_logf(x); }
#else
__device__ __forceinline__ float log2_fast(float x) { return log2f(x); }
#endif

// Online base-2 LSE update, single exp2 per element (branch-free select).
__device__ __forceinline__ void lse_update(float& m, float& s, float u) {
  float mn = fmaxf(m, u);
  float e = exp2_fast(fminf(m, u) - mn);
  bool gt = u > m;
  s = fmaf(s, gt ? e : 1.0f, gt ? 1.0f : e);
  m = mn;
}

// Merge two (m,s) LSE partials.
__device__ __forceinline__ void lse_merge(float& m, float& s, float m2, float s2) {
  float mn = fmaxf(m, m2);
  s = fmaf(s, exp2_fast(m - mn), s2 * exp2_fast(m2 - mn));
  m = mn;
}

// norms + Pf init (pm=0, ps = strip==0 ? 1 : 0  ==> merged f value 0).
__global__ __launch_bounds__(256) void init_kernel(
    const float* __restrict__ x, float* __restrict__ norms,
    float* __restrict__ pmF, float* __restrict__ psF) {
  int idx = blockIdx.x * 256 + threadIdx.x;
  if (idx < NT * NPTS) {
    const float* row = x + (size_t)idx * DIM;
    float d0 = 0.f, d1 = 0.f, d2 = 0.f, d3 = 0.f;
#pragma unroll
    for (int k = 0; k < DIM; k += 4) {
      d0 = fmaf(row[k + 0], row[k + 0], d0);
      d1 = fmaf(row[k + 1], row[k + 1], d1);
      d2 = fmaf(row[k + 2], row[k + 2], d2);
      d3 = fmaf(row[k + 3], row[k + 3], d3);
    }
    norms[idx] = (d0 + d1) + (d2 + d3);
  }
  if (idx < NPAIR * NSTRIP * NPTS) {
    int s = (idx / NPTS) % NSTRIP;
    pmF[idx] = 0.f;
    psF[idx] = (s == 0) ? 1.f : 0.f;
  }
}

// C[p][i][j] = 0.5*(|x_i|^2+|y_j|^2) - x_i.y_j, stored fp16 in BOTH layouts:
// C row-major [p][i][j] and CT transposed [p][j][i].
__global__ __launch_bounds__(256) void cmat_kernel(
    const float* __restrict__ x, const float* __restrict__ norms,
    __half* __restrict__ C, __half* __restrict__ CT) {
  int bid = blockIdx.x;
  int p = bid >> 10;
  int ib = (bid >> 5) & 31;
  int jb = bid & 31;
  const float* xr = x + (size_t)p * NPTS * DIM;
  const float* yr = x + (size_t)(p + 1) * NPTS * DIM;
  __shared__ float xs[64][DIM];
  __shared__ float ys[64][DIM + 1];
  __shared__ __half cc[64][66];   // 64x64 tile, row pad 66 (even, 132B stride)
  int tid = threadIdx.x;
  for (int r = 0; r < 8; ++r) {
    int e = (r << 8) + tid;
    int i = e >> 5, k = e & 31;
    xs[i][k] = xr[(size_t)(ib << 6) * DIM + e];
    ys[i][k] = yr[(size_t)(jb << 6) * DIM + e];
  }
  __syncthreads();
  int jloc = tid & 63, istrip = tid >> 6;
  float nyv = norms[(p + 1) * NPTS + (jb << 6) + jloc];
  for (int ii = 0; ii < 16; ++ii) {
    int i = (istrip << 4) + ii;
    float d0 = 0.f, d1 = 0.f, d2 = 0.f, d3 = 0.f;
#pragma unroll
    for (int k = 0; k < DIM; k += 4) {
      d0 = fmaf(xs[i][k + 0], ys[jloc][k + 0], d0);
      d1 = fmaf(xs[i][k + 1], ys[jloc][k + 1], d1);
      d2 = fmaf(xs[i][k + 2], ys[jloc][k + 2], d2);
      d3 = fmaf(xs[i][k + 3], ys[jloc][k + 3], d3);
    }
    float nxv = norms[p * NPTS + (ib << 6) + i];
    cc[i][jloc] = __float2half_rn(fmaf(0.5f, nxv + nyv, -((d0 + d1) + (d2 + d3))));
  }
  __syncthreads();
  for (int r = 0; r < 8; ++r) {
    int e = (r << 8) + tid;
    int row = e >> 5, h2 = e & 31;
    __half2 v = *(__half2*)&cc[row][2 * h2];
    ((__half2*)(C + ((size_t)p * NPTS + (ib << 6) + row) * NPTS + (jb << 6)))[h2] = v;
  }
  for (int r = 0; r < 8; ++r) {
    int e = (r << 8) + tid;
    int col = e >> 5, h2 = e & 31;
    __half2 v = __halves2half2(cc[2 * h2][col], cc[2 * h2 + 1][col]);
    ((__half2*)(CT + ((size_t)p * NPTS + (jb << 6) + col) * NPTS + (ib << 6)))[h2] = v;
  }
}

// One Sinkhorn half-sweep, fence/atomic-free.
//  Step A: rebuild needed src rows from producer partials:
//          src[row] = (csp*(M+log2(S)) + cbp) * kk   (merged over NSTRIP)
//  Step B: partial-reduce this block's 128x128 tile of M.
//  Step C: write (m,s) partials for its 128 cols at [p][strip][col].
// Cross-dispatch ordering (stream serialization) is the only synchronization.
__global__ __launch_bounds__(256) void sweep_kernel(
    const __half2* __restrict__ M,
    const float* __restrict__ pmIn, const float* __restrict__ psIn,
    float* __restrict__ pmOut, float* __restrict__ psOut,
    float kk, float csp, float cbp) {
  int b = blockIdx.x;
  int p = b >> 8;              // 256 blocks per pair
  int grp = (b >> 4) & (NGRP - 1);
  int strip = b & (NSTRIP - 1);
  int tid = threadIdx.x;
  int r0 = strip * SROWS;
  __shared__ float srck[SROWS];
  if (tid < SROWS) {           // coalesced: 128 threads x consecutive rows
    const float* pmr = pmIn + (size_t)p * NSTRIP * NPTS + r0 + tid;
    const float* psr = psIn + (size_t)p * NSTRIP * NPTS + r0 + tid;
    float Mv = pmr[0], Sv = psr[0];
#pragma unroll
    for (int s = 1; s < NSTRIP; ++s)
      lse_merge(Mv, Sv, pmr[(size_t)s * NPTS], psr[(size_t)s * NPTS]);
    srck[tid] = fmaf(csp, Mv + log2_fast(Sv), cbp) * kk;
  }
  __syncthreads();
  int cpair = tid & 63;        // 2 adjacent cols per thread (half2)
  int sub = tid >> 6;          // 4 row sub-chains of 32
  const __half2* Mp = M + ((size_t)p * NPTS + r0 + sub * SUBROWS) * (NPTS / 2)
                        + grp * (GCOLS / 2) + cpair;
  const float* sk = srck + sub * SUBROWS;
  float ma0 = -INFINITY, ma1 = -INFINITY, mb0 = -INFINITY, mb1 = -INFINITY;
  float sa0 = 0.f, sa1 = 0.f, sb0 = 0.f, sb1 = 0.f;
#pragma unroll 4
  for (int ii = 0; ii < SUBROWS; ii += 2) {
    float2 ca = __half22float2(Mp[(size_t)ii * (NPTS / 2)]);
    float2 cb2 = __half22float2(Mp[(size_t)(ii + 1) * (NPTS / 2)]);
    float fa = sk[ii];
    float fb = sk[ii + 1];
    lse_update(ma0, sa0, fmaf(-kk, ca.x, fa));
    lse_update(ma1, sa1, fmaf(-kk, ca.y, fa));
    lse_update(mb0, sb0, fmaf(-kk, cb2.x, fb));
    lse_update(mb1, sb1, fmaf(-kk, cb2.y, fb));
  }
  lse_merge(ma0, sa0, mb0, sb0);
  lse_merge(ma1, sa1, mb1, sb1);
  __shared__ float lm[4][GCOLS], ls[4][GCOLS];
  lm[sub][2 * cpair] = ma0;     ls[sub][2 * cpair] = sa0;
  lm[sub][2 * cpair + 1] = ma1; ls[sub][2 * cpair + 1] = sa1;
  __syncthreads();
  if (tid < GCOLS) {
    float Mv = lm[0][tid], Sv = ls[0][tid];
    lse_merge(Mv, Sv, lm[1][tid], ls[1][tid]);
    lse_merge(Mv, Sv, lm[2][tid], ls[2][tid]);
    lse_merge(Mv, Sv, lm[3][tid], ls[3][tid]);
    size_t o = ((size_t)p * NSTRIP + strip) * NPTS + grp * GCOLS + tid;
    pmOut[o] = Mv;
    psOut[o] = Sv;
  }
}

// Final: merge partials -> f, g values (last iteration's constants), sum.
__global__ __launch_bounds__(256) void out_kernel(
    const float* __restrict__ pmF, const float* __restrict__ psF,
    const float* __restrict__ pmG, const float* __restrict__ psG,
    float cs, float cb, float* __restrict__ out) {
  int p = blockIdx.x;
  int tid = threadIdx.x;
  float acc = 0.f;
  for (int i = tid; i < NPTS; i += 256) {
    size_t base = (size_t)p * NSTRIP * NPTS + i;
    float Mv = pmF[base], Sv = psF[base];
#pragma unroll
    for (int s = 1; s < NSTRIP; ++s)
      lse_merge(Mv, Sv, pmF[base + (size_t)s * NPTS], psF[base + (size_t)s * NPTS]);
    acc += fmaf(cs, Mv + log2_fast(Sv), cb);
    float Mg = pmG[base], Sg = psG[base];
#pragma unroll
    for (int s = 1; s < NSTRIP; ++s)
      lse_merge(Mg, Sg, pmG[base + (size_t)s * NPTS], psG[base + (size_t)s * NPTS]);
    acc += fmaf(cs, Mg + log2_fast(Sg), cb);
  }
  __shared__ float red[256];
  red[tid] = acc;
  __syncthreads();
  for (int h = 128; h > 0; h >>= 1) {
    if (tid < h) red[tid] += red[tid + h];
    __syncthreads();
  }
  if (tid == 0) atomicAdd(out, red[0] * (0.05f / (float)NPTS));
}

extern "C" void kernel_launch(void* const* d_in, const int* in_sizes, int n_in,
                              void* d_out, int out_size, void* d_ws, size_t ws_size,
                              hipStream_t stream) {
  const float* x = (const float*)d_in[0];
  float* out = (float*)d_out;
  const size_t PSZ = (size_t)NPAIR * NSTRIP * NPTS;   // 163840 floats / array
  float* norms = (float*)d_ws;
  float* pmF = norms + NT * NPTS;
  float* psF = pmF + PSZ;
  float* pmG = psF + PSZ;
  float* psG = pmG + PSZ;
  size_t head = (char*)(psG + PSZ) - (char*)d_ws;
  size_t coff = (head + 255) & ~(size_t)255;
  __half* C = (__half*)((char*)d_ws + coff);
  __half* CT = C + (size_t)NPAIR * NPTS * NPTS;

  hipMemsetAsync(d_out, 0, sizeof(float), stream);
  init_kernel<<<(int)((PSZ + 255) / 256), 256, 0, stream>>>(x, norms, pmF, psF);
  cmat_kernel<<<NPAIR * 1024, 256, 0, stream>>>(x, norms, C, CT);

  const double LN2 = 0.6931471805599453;
  const double LOGN = 7.624618986159398;  // ln(2048)
  const int NBLK = NPAIR * NGRP * NSTRIP; // 1280
  float csf = 0.f, cbf = 0.f;             // constants of the producer of Pf
  for (int t = 0; t < 80; ++t) {
    double eps = 100.0 * pow(0.95, 2.0 * (double)t);
    if (eps < 0.05) eps = 0.05;
    float kk = (float)(1.0 / (eps * LN2));
    float cs = (float)(-eps * LN2);
    float cb = (float)(eps * LOGN);
    // g-partials: sweep C (rows=i), src = f rebuilt from Pf with (csf, cbf)
    sweep_kernel<<<NBLK, 256, 0, stream>>>((const __half2*)C, pmF, psF,
                                           pmG, psG, kk, csf, cbf);
    // f-partials: sweep CT (rows=j), src = g rebuilt from Pg with (cs, cb)
    sweep_kernel<<<NBLK, 256, 0, stream>>>((const __half2*)CT, pmG, psG,
                                           pmF, psF, kk, cs, cb);
    csf = cs; cbf = cb;
  }
  out_kernel<<<NPAIR, 256, 0, stream>>>(pmF, psF, pmG, psG, csf, cbf, out);
}

// Round 13
// 1702.864 us; speedup vs baseline: 11.6701x; 1.1449x over previous
//
#include <hip/hip_runtime.h>
#include <hip/hip_fp16.h>
#include <math.h>

#define NPTS 2048
#define DIM 32
#define NPAIR 5
#define NT 6
#define NSTRIP 16      // row strips per sweep (cross-dispatch partials)
#define NGRP 16        // col groups per sweep
#define GCOLS 128      // cols per block
#define SROWS 128      // rows per strip (per block)

#if __has_builtin(__builtin_amdgcn_exp2f)
__device__ __forceinline__ float exp2_fast(float x) { return __builtin_amdgcn_exp2f(x); }
#else
__device__ __forceinline__ float exp2_fast(float x) { return exp2f(x); }
#endif
#if __has_builtin(__builtin_amdgcn_logf)
__device__ __forceinline__ float log2_fast(float x) { return __builtin_amdgcn_logf(x); }
#else
__device__ __forceinline__ float log2_fast(float x) { return log2f(x); }
#endif

// Merge two (m,s) LSE partials.
__device__ __forceinline__ void lse_merge(float& m, float& s, float m2, float s2) {
  float mn = fmaxf(m, m2);
  s = fmaf(s, exp2_fast(m - mn), s2 * exp2_fast(m2 - mn));
  m = mn;
}

// norms + Pf init (pm=0, ps = strip==0 ? 1 : 0  ==> merged f value 0).
__global__ __launch_bounds__(256) void init_kernel(
    const float* __restrict__ x, float* __restrict__ norms,
    float* __restrict__ pmF, float* __restrict__ psF) {
  int idx = blockIdx.x * 256 + threadIdx.x;
  if (idx < NT * NPTS) {
    const float* row = x + (size_t)idx * DIM;
    float d0 = 0.f, d1 = 0.f, d2 = 0.f, d3 = 0.f;
#pragma unroll
    for (int k = 0; k < DIM; k += 4) {
      d0 = fmaf(row[k + 0], row[k + 0], d0);
      d1 = fmaf(row[k + 1], row[k + 1], d1);
      d2 = fmaf(row[k + 2], row[k + 2], d2);
      d3 = fmaf(row[k + 3], row[k + 3], d3);
    }
    norms[idx] = (d0 + d1) + (d2 + d3);
  }
  if (idx < NPAIR * NSTRIP * NPTS) {
    int s = (idx / NPTS) % NSTRIP;
    pmF[idx] = 0.f;
    psF[idx] = (s == 0) ? 1.f : 0.f;
  }
}

// C[p][i][j] = 0.5*(|x_i|^2+|y_j|^2) - x_i.y_j, stored fp16 in BOTH layouts:
// C row-major [p][i][j] and CT transposed [p][j][i].
__global__ __launch_bounds__(256) void cmat_kernel(
    const float* __restrict__ x, const float* __restrict__ norms,
    __half* __restrict__ C, __half* __restrict__ CT) {
  int bid = blockIdx.x;
  int p = bid >> 10;
  int ib = (bid >> 5) & 31;
  int jb = bid & 31;
  const float* xr = x + (size_t)p * NPTS * DIM;
  const float* yr = x + (size_t)(p + 1) * NPTS * DIM;
  __shared__ float xs[64][DIM];
  __shared__ float ys[64][DIM + 1];
  __shared__ __half cc[64][66];   // 64x64 tile, row pad 66 (even, 132B stride)
  int tid = threadIdx.x;
  for (int r = 0; r < 8; ++r) {
    int e = (r << 8) + tid;
    int i = e >> 5, k = e & 31;
    xs[i][k] = xr[(size_t)(ib << 6) * DIM + e];
    ys[i][k] = yr[(size_t)(jb << 6) * DIM + e];
  }
  __syncthreads();
  int jloc = tid & 63, istrip = tid >> 6;
  float nyv = norms[(p + 1) * NPTS + (jb << 6) + jloc];
  for (int ii = 0; ii < 16; ++ii) {
    int i = (istrip << 4) + ii;
    float d0 = 0.f, d1 = 0.f, d2 = 0.f, d3 = 0.f;
#pragma unroll
    for (int k = 0; k < DIM; k += 4) {
      d0 = fmaf(xs[i][k + 0], ys[jloc][k + 0], d0);
      d1 = fmaf(xs[i][k + 1], ys[jloc][k + 1], d1);
      d2 = fmaf(xs[i][k + 2], ys[jloc][k + 2], d2);
      d3 = fmaf(xs[i][k + 3], ys[jloc][k + 3], d3);
    }
    float nxv = norms[p * NPTS + (ib << 6) + i];
    cc[i][jloc] = __float2half_rn(fmaf(0.5f, nxv + nyv, -((d0 + d1) + (d2 + d3))));
  }
  __syncthreads();
  for (int r = 0; r < 8; ++r) {
    int e = (r << 8) + tid;
    int row = e >> 5, h2 = e & 31;
    __half2 v = *(__half2*)&cc[row][2 * h2];
    ((__half2*)(C + ((size_t)p * NPTS + (ib << 6) + row) * NPTS + (jb << 6)))[h2] = v;
  }
  for (int r = 0; r < 8; ++r) {
    int e = (r << 8) + tid;
    int col = e >> 5, h2 = e & 31;
    __half2 v = __halves2half2(cc[2 * h2][col], cc[2 * h2 + 1][col]);
    ((__half2*)(CT + ((size_t)p * NPTS + (jb << 6) + col) * NPTS + (ib << 6)))[h2] = v;
  }
}

// One Sinkhorn half-sweep, fence/atomic-free.
//  Step A: rebuild needed src rows from producer partials (all 256 threads:
//          2 threads/row x 8 strips, then pairwise LDS merge).
//  Step B: 8x8 register blocking: thread (cg,rl) owns cols cg*8..+8 of rows
//          rl*8..+8; one float4 (16B) load per row => 1024B/wave-instruction,
//          8 loads in flight. Batched 8-row max + one exp2 pass per col.
//  Step C: 16-way cross-rowlane merge in padded LDS; write (m,s) partials.
// Cross-dispatch ordering (stream serialization) is the only synchronization.
__global__ __launch_bounds__(256) void sweep_kernel(
    const __half2* __restrict__ M,
    const float* __restrict__ pmIn, const float* __restrict__ psIn,
    float* __restrict__ pmOut, float* __restrict__ psOut,
    float kk, float csp, float cbp) {
  int b = blockIdx.x;
  int p = b >> 8;              // 256 blocks per pair
  int grp = (b >> 4) & (NGRP - 1);
  int strip = b & (NSTRIP - 1);
  int tid = threadIdx.x;
  int r0 = strip * SROWS;
  // ---- Step A ----
  __shared__ float sAm[2][SROWS], sAs[2][SROWS];
  __shared__ float srck[SROWS];
  {
    int row = tid & 127;
    int half = tid >> 7;       // strips half*8 .. +8
    const float* pmr = pmIn + ((size_t)p * NSTRIP + half * 8) * NPTS + r0 + row;
    const float* psr = psIn + ((size_t)p * NSTRIP + half * 8) * NPTS + r0 + row;
    float Mv = pmr[0], Sv = psr[0];
#pragma unroll
    for (int s = 1; s < 8; ++s)
      lse_merge(Mv, Sv, pmr[(size_t)s * NPTS], psr[(size_t)s * NPTS]);
    sAm[half][row] = Mv; sAs[half][row] = Sv;
  }
  __syncthreads();
  if (tid < SROWS) {
    float Mv = sAm[0][tid], Sv = sAs[0][tid];
    lse_merge(Mv, Sv, sAm[1][tid], sAs[1][tid]);
    srck[tid] = fmaf(csp, Mv + log2_fast(Sv), cbp) * kk;
  }
  __syncthreads();
  // ---- Step B ----
  int cg = tid & 15;           // col octet: cols grp*128 + cg*8 .. +8
  int rl = tid >> 4;           // row lane: rows r0 + rl*8 .. +8
  const float4* base = (const float4*)(M + ((size_t)p * NPTS + r0 + rl * 8) * (NPTS / 2)
                                         + grp * (GCOLS / 2)) + cg;
  float4 raw[8];
#pragma unroll
  for (int r = 0; r < 8; ++r) raw[r] = base[(size_t)r * (NPTS / 8)];   // row stride: 2048 halfs = 256 float4
  float fa_r[8];
#pragma unroll
  for (int r = 0; r < 8; ++r) fa_r[r] = srck[rl * 8 + r];
  float m[8], s[8];
#pragma unroll
  for (int c = 0; c < 8; ++c) {
    float u[8];
#pragma unroll
    for (int r = 0; r < 8; ++r) {
      __half2 h2v = reinterpret_cast<const __half2*>(&raw[r])[c >> 1];
      float cv = (c & 1) ? __high2float(h2v) : __low2float(h2v);
      u[r] = fmaf(-kk, cv, fa_r[r]);
    }
    float mx = fmaxf(fmaxf(fmaxf(u[0], u[1]), fmaxf(u[2], u[3])),
                     fmaxf(fmaxf(u[4], u[5]), fmaxf(u[6], u[7])));
    float ssum = ((exp2_fast(u[0] - mx) + exp2_fast(u[1] - mx)) +
                  (exp2_fast(u[2] - mx) + exp2_fast(u[3] - mx))) +
                 ((exp2_fast(u[4] - mx) + exp2_fast(u[5] - mx)) +
                  (exp2_fast(u[6] - mx) + exp2_fast(u[7] - mx)));
    m[c] = mx; s[c] = ssum;    // single batch per thread: no merge needed
  }
  // ---- Step C ----
  __shared__ float lmm[16][GCOLS + 2], lss[16][GCOLS + 2];  // pad: 4-way banks
#pragma unroll
  for (int c = 0; c < 8; ++c) {
    lmm[rl][cg * 8 + c] = m[c];
    lss[rl][cg * 8 + c] = s[c];
  }
  __syncthreads();
  if (tid < GCOLS) {
    float Mv = lmm[0][tid], Sv = lss[0][tid];
#pragma unroll
    for (int k = 1; k < 16; ++k) lse_merge(Mv, Sv, lmm[k][tid], lss[k][tid]);
    size_t o = ((size_t)p * NSTRIP + strip) * NPTS + grp * GCOLS + tid;
    pmOut[o] = Mv;
    psOut[o] = Sv;
  }
}

// Final: merge partials -> f, g values (last iteration's constants), sum.
// 160 blocks (5 pairs x 32 chunks of 64 rows) to kill the 75us latency tail.
__global__ __launch_bounds__(256) void out_kernel(
    const float* __restrict__ pmF, const float* __restrict__ psF,
    const float* __restrict__ pmG, const float* __restrict__ psG,
    float cs, float cb, float* __restrict__ out) {
  int p = blockIdx.x >> 5;
  int chunk = blockIdx.x & 31;
  int tid = threadIdx.x;
  int r = tid & 63;
  int q = tid >> 6;            // strips q*4 .. +4
  int row = chunk * 64 + r;
  size_t base = ((size_t)p * NSTRIP + q * 4) * NPTS + row;
  float Mf = pmF[base], Sf = psF[base];
  float Mg = pmG[base], Sg = psG[base];
#pragma unroll
  for (int k = 1; k < 4; ++k) {
    lse_merge(Mf, Sf, pmF[base + (size_t)k * NPTS], psF[base + (size_t)k * NPTS]);
    lse_merge(Mg, Sg, pmG[base + (size_t)k * NPTS], psG[base + (size_t)k * NPTS]);
  }
  __shared__ float lmF[4][64], lsF[4][64], lmG[4][64], lsG[4][64];
  lmF[q][r] = Mf; lsF[q][r] = Sf;
  lmG[q][r] = Mg; lsG[q][r] = Sg;
  __syncthreads();
  float v = 0.f;
  if (q == 0) {
    float M1 = lmF[0][r], S1 = lsF[0][r];
    lse_merge(M1, S1, lmF[1][r], lsF[1][r]);
    lse_merge(M1, S1, lmF[2][r], lsF[2][r]);
    lse_merge(M1, S1, lmF[3][r], lsF[3][r]);
    v = fmaf(cs, M1 + log2_fast(S1), cb);
    float M2 = lmG[0][r], S2 = lsG[0][r];
    lse_merge(M2, S2, lmG[1][r], lsG[1][r]);
    lse_merge(M2, S2, lmG[2][r], lsG[2][r]);
    lse_merge(M2, S2, lmG[3][r], lsG[3][r]);
    v += fmaf(cs, M2 + log2_fast(S2), cb);
  }
  __shared__ float red[256];
  red[tid] = v;
  __syncthreads();
  for (int h = 128; h > 0; h >>= 1) {
    if (tid < h) red[tid] += red[tid + h];
    __syncthreads();
  }
  if (tid == 0) atomicAdd(out, red[0] * (0.05f / (float)NPTS));
}

extern "C" void kernel_launch(void* const* d_in, const int* in_sizes, int n_in,
                              void* d_out, int out_size, void* d_ws, size_t ws_size,
                              hipStream_t stream) {
  const float* x = (const float*)d_in[0];
  float* out = (float*)d_out;
  const size_t PSZ = (size_t)NPAIR * NSTRIP * NPTS;   // 163840 floats / array
  float* norms = (float*)d_ws;
  float* pmF = norms + NT * NPTS;
  float* psF = pmF + PSZ;
  float* pmG = psF + PSZ;
  float* psG = pmG + PSZ;
  size_t head = (char*)(psG + PSZ) - (char*)d_ws;
  size_t coff = (head + 255) & ~(size_t)255;
  __half* C = (__half*)((char*)d_ws + coff);
  __half* CT = C + (size_t)NPAIR * NPTS * NPTS;

  hipMemsetAsync(d_out, 0, sizeof(float), stream);
  init_kernel<<<(int)((PSZ + 255) / 256), 256, 0, stream>>>(x, norms, pmF, psF);
  cmat_kernel<<<NPAIR * 1024, 256, 0, stream>>>(x, norms, C, CT);

  const double LN2 = 0.6931471805599453;
  const double LOGN = 7.624618986159398;  // ln(2048)
  const int NBLK = NPAIR * NGRP * NSTRIP; // 1280
  float csf = 0.f, cbf = 0.f;             // constants of the producer of Pf
  for (int t = 0; t < 80; ++t) {
    double eps = 100.0 * pow(0.95, 2.0 * (double)t);
    if (eps < 0.05) eps = 0.05;
    float kk = (float)(1.0 / (eps * LN2));
    float cs = (float)(-eps * LN2);
    float cb = (float)(eps * LOGN);
    // g-partials: sweep C (rows=i), src = f rebuilt from Pf with (csf, cbf)
    sweep_kernel<<<NBLK, 256, 0, stream>>>((const __half2*)C, pmF, psF,
                                           pmG, psG, kk, csf, cbf);
    // f-partials: sweep CT (rows=j), src = g rebuilt from Pg with (cs, cb)
    sweep_kernel<<<NBLK, 256, 0, stream>>>((const __half2*)CT, pmG, psG,
                                           pmF, psF, kk, cs, cb);
    csf = cs; cbf = cb;
  }
  out_kernel<<<NPAIR * 32, 256, 0, stream>>>(pmF, psF, pmG, psG, csf, cbf, out);
}

// Round 16
// 1334.032 us; speedup vs baseline: 14.8967x; 1.2765x over previous
//
#include <hip/hip_runtime.h>
#include <hip/hip_fp16.h>
#include <math.h>

#define NPTS 2048
#define DIM 32
#define NPAIR 5
#define NT 6
#define NSTRIP 16      // row strips per sweep (cross-dispatch partials)
#define NGRP 16        // col groups per sweep
#define GCOLS 128      // cols per block
#define SROWS 128      // rows per strip (per block)

typedef _Float16 half8 __attribute__((ext_vector_type(8)));
typedef float f32x16 __attribute__((ext_vector_type(16)));

#if __has_builtin(__builtin_amdgcn_exp2f)
__device__ __forceinline__ float exp2_fast(float x) { return __builtin_amdgcn_exp2f(x); }
#else
__device__ __forceinline__ float exp2_fast(float x) { return exp2f(x); }
#endif
#if __has_builtin(__builtin_amdgcn_logf)
__device__ __forceinline__ float log2_fast(float x) { return __builtin_amdgcn_logf(x); }
#else
__device__ __forceinline__ float log2_fast(float x) { return log2f(x); }
#endif

// Merge two (m,s) LSE partials.
__device__ __forceinline__ void lse_merge(float& m, float& s, float m2, float s2) {
  float mn = fmaxf(m, m2);
  s = fmaf(s, exp2_fast(m - mn), s2 * exp2_fast(m2 - mn));
  m = mn;
}

// norms + fp16 copy of x + Pf init (pm=0, ps = strip==0 ? 1:0 => f = 0).
__global__ __launch_bounds__(256) void init_kernel(
    const float* __restrict__ x, float* __restrict__ norms,
    _Float16* __restrict__ xh, float* __restrict__ pmF, float* __restrict__ psF) {
  int idx = blockIdx.x * 256 + threadIdx.x;
  if (idx < NT * NPTS) {
    const float* row = x + (size_t)idx * DIM;
    float d0 = 0.f, d1 = 0.f, d2 = 0.f, d3 = 0.f;
#pragma unroll
    for (int k = 0; k < DIM; k += 4) {
      d0 = fmaf(row[k + 0], row[k + 0], d0);
      d1 = fmaf(row[k + 1], row[k + 1], d1);
      d2 = fmaf(row[k + 2], row[k + 2], d2);
      d3 = fmaf(row[k + 3], row[k + 3], d3);
    }
    norms[idx] = (d0 + d1) + (d2 + d3);
    _Float16* xr = xh + (size_t)idx * DIM;
#pragma unroll
    for (int k = 0; k < DIM; ++k) xr[k] = (_Float16)row[k];
  }
  if (idx < NPAIR * NSTRIP * NPTS) {
    int s = (idx / NPTS) % NSTRIP;
    pmF[idx] = 0.f;
    psF[idx] = (s == 0) ? 1.f : 0.f;
  }
}

// One Sinkhorn half-sweep, C-matrix-free (MFMA recompute), fence/atomic-free.
//   u_ij = (src_i - C_ij)*kk = a_i + b_j + kk*(xA_i . xB_j)
//   a_i  = kk*(src_i - 0.5*nA_i)   (folded into Step A)
//   b_j  = -0.5*kk*nB_j            (added at partial write)
// dir=0: g-sweep (A-side = timepoint p, B-side = p+1); dir=1: f-sweep (swap).
// Step A: rebuild src rows from producer partials -> srck = a_i.
// Step B: per wave (row band of 32): 4 col-tiles of 32; per tile 2 MFMAs
//         (32x32x16 f16, K=32). C/D: col=lane&31, row=(reg&3)+8*(reg>>2)
//         +4*(lane>>5) -> 16 regs = 16 rows of ONE column. In-lane 16-row
//         LSE + shfl_xor(32) = full 32-row column reduce.
// Step C: 4-way band merge in LDS; +b_j; write (m,s) strip partial.
__global__ __launch_bounds__(256) void sweep_kernel(
    const _Float16* __restrict__ xh, const float* __restrict__ norms,
    const float* __restrict__ pmIn, const float* __restrict__ psIn,
    float* __restrict__ pmOut, float* __restrict__ psOut,
    int dir, float kk, float csp, float cbp) {
  int b = blockIdx.x;
  int p = b >> 8;              // 256 blocks per pair
  int grp = (b >> 4) & (NGRP - 1);
  int strip = b & (NSTRIP - 1);
  int tid = threadIdx.x;
  int r0 = strip * SROWS;
  int c0g = grp * GCOLS;
  int aT = p + dir;            // rows-side timepoint
  int bT = p + 1 - dir;        // cols-side timepoint
  // ---- Step A: srck[row] = kk*(src_row - 0.5*nA_row) ----
  __shared__ float sAm[2][SROWS], sAs[2][SROWS];
  __shared__ float srck[SROWS];
  {
    int row = tid & 127;
    int half = tid >> 7;       // strips half*8 .. +8
    const float* pmr = pmIn + ((size_t)p * NSTRIP + half * 8) * NPTS + r0 + row;
    const float* psr = psIn + ((size_t)p * NSTRIP + half * 8) * NPTS + r0 + row;
    float Mv = pmr[0], Sv = psr[0];
#pragma unroll
    for (int s = 1; s < 8; ++s)
      lse_merge(Mv, Sv, pmr[(size_t)s * NPTS], psr[(size_t)s * NPTS]);
    sAm[half][row] = Mv; sAs[half][row] = Sv;
  }
  __syncthreads();
  if (tid < SROWS) {
    float Mv = sAm[0][tid], Sv = sAs[0][tid];
    lse_merge(Mv, Sv, sAm[1][tid], sAs[1][tid]);
    float fv = fmaf(csp, Mv + log2_fast(Sv), cbp);
    srck[tid] = (fv - 0.5f * norms[(size_t)aT * NPTS + r0 + tid]) * kk;
  }
  __syncthreads();
  // ---- Step B ----
  int w = tid >> 6;            // wave = row band (32 rows)
  int lane = tid & 63;
  int l31 = lane & 31, lhi = lane >> 5;
  // A fragments for this wave's rows (shared across the 4 col tiles)
  const _Float16* arow = xh + ((size_t)aT * NPTS + r0 + w * 32 + l31) * DIM + 8 * lhi;
  half8 a0 = *(const half8*)(arow);        // k 8*lhi .. +8
  half8 a1 = *(const half8*)(arow + 16);   // k 16+8*lhi .. +8
  // a-values for the 16 acc rows (row depends on reg & lane-half only)
  float av[16];
#pragma unroll
  for (int reg = 0; reg < 16; ++reg) {
    int rr = (reg & 3) + 8 * (reg >> 2) + 4 * lhi;
    av[reg] = srck[w * 32 + rr];
  }
  __shared__ float lmm[4][GCOLS + 2], lss[4][GCOLS + 2];
  for (int tg = 0; tg < 4; ++tg) {
    const _Float16* brow = xh + ((size_t)bT * NPTS + c0g + tg * 32 + l31) * DIM + 8 * lhi;
    half8 b0 = *(const half8*)(brow);
    half8 b1 = *(const half8*)(brow + 16);
    f32x16 acc = {};
    acc = __builtin_amdgcn_mfma_f32_32x32x16_f16(a0, b0, acc, 0, 0, 0);
    acc = __builtin_amdgcn_mfma_f32_32x32x16_f16(a1, b1, acc, 0, 0, 0);
    float v[16];
#pragma unroll
    for (int reg = 0; reg < 16; ++reg) v[reg] = fmaf(kk, acc[reg], av[reg]);
    float mx = fmaxf(fmaxf(fmaxf(fmaxf(v[0], v[1]), fmaxf(v[2], v[3])),
                           fmaxf(fmaxf(v[4], v[5]), fmaxf(v[6], v[7]))),
                     fmaxf(fmaxf(fmaxf(v[8], v[9]), fmaxf(v[10], v[11])),
                           fmaxf(fmaxf(v[12], v[13]), fmaxf(v[14], v[15]))));
    float ss = 0.f;
#pragma unroll
    for (int reg = 0; reg < 16; ++reg) ss += exp2_fast(v[reg] - mx);
    // merge with partner lane (same col, other 16 rows)
    float mo = __shfl_xor(mx, 32, 64);
    float so = __shfl_xor(ss, 32, 64);
    lse_merge(mx, ss, mo, so);
    if (lane < 32) {
      lmm[w][tg * 32 + lane] = mx;
      lss[w][tg * 32 + lane] = ss;
    }
  }
  __syncthreads();
  // ---- Step C ----
  if (tid < GCOLS) {
    float Mv = lmm[0][tid], Sv = lss[0][tid];
    lse_merge(Mv, Sv, lmm[1][tid], lss[1][tid]);
    lse_merge(Mv, Sv, lmm[2][tid], lss[2][tid]);
    lse_merge(Mv, Sv, lmm[3][tid], lss[3][tid]);
    float bj = -0.5f * kk * norms[(size_t)bT * NPTS + c0g + tid];
    size_t o = ((size_t)p * NSTRIP + strip) * NPTS + c0g + tid;
    pmOut[o] = Mv + bj;
    psOut[o] = Sv;
  }
}

// Final: merge partials -> f, g values (last iteration's constants), sum.
// 160 blocks (5 pairs x 32 chunks of 64 rows).
__global__ __launch_bounds__(256) void out_kernel(
    const float* __restrict__ pmF, const float* __restrict__ psF,
    const float* __restrict__ pmG, const float* __restrict__ psG,
    float cs, float cb, float* __restrict__ out) {
  int p = blockIdx.x >> 5;
  int chunk = blockIdx.x & 31;
  int tid = threadIdx.x;
  int r = tid & 63;
  int q = tid >> 6;            // strips q*4 .. +4
  int row = chunk * 64 + r;
  size_t base = ((size_t)p * NSTRIP + q * 4) * NPTS + row;
  float Mf = pmF[base], Sf = psF[base];
  float Mg = pmG[base], Sg = psG[base];
#pragma unroll
  for (int k = 1; k < 4; ++k) {
    lse_merge(Mf, Sf, pmF[base + (size_t)k * NPTS], psF[base + (size_t)k * NPTS]);
    lse_merge(Mg, Sg, pmG[base + (size_t)k * NPTS], psG[base + (size_t)k * NPTS]);
  }
  __shared__ float lmF[4][64], lsF[4][64], lmG[4][64], lsG[4][64];
  lmF[q][r] = Mf; lsF[q][r] = Sf;
  lmG[q][r] = Mg; lsG[q][r] = Sg;
  __syncthreads();
  float v = 0.f;
  if (q == 0) {
    float M1 = lmF[0][r], S1 = lsF[0][r];
    lse_merge(M1, S1, lmF[1][r], lsF[1][r]);
    lse_merge(M1, S1, lmF[2][r], lsF[2][r]);
    lse_merge(M1, S1, lmF[3][r], lsF[3][r]);
    v = fmaf(cs, M1 + log2_fast(S1), cb);
    float M2 = lmG[0][r], S2 = lsG[0][r];
    lse_merge(M2, S2, lmG[1][r], lsG[1][r]);
    lse_merge(M2, S2, lmG[2][r], lsG[2][r]);
    lse_merge(M2, S2, lmG[3][r], lsG[3][r]);
    v += fmaf(cs, M2 + log2_fast(S2), cb);
  }
  __shared__ float red[256];
  red[tid] = v;
  __syncthreads();
  for (int h = 128; h > 0; h >>= 1) {
    if (tid < h) red[tid] += red[tid + h];
    __syncthreads();
  }
  if (tid == 0) atomicAdd(out, red[0] * (0.05f / (float)NPTS));
}

extern "C" void kernel_launch(void* const* d_in, const int* in_sizes, int n_in,
                              void* d_out, int out_size, void* d_ws, size_t ws_size,
                              hipStream_t stream) {
  const float* x = (const float*)d_in[0];
  float* out = (float*)d_out;
  const size_t PSZ = (size_t)NPAIR * NSTRIP * NPTS;   // 163840 floats / array
  float* norms = (float*)d_ws;
  float* pmF = norms + NT * NPTS;
  float* psF = pmF + PSZ;
  float* pmG = psF + PSZ;
  float* psG = pmG + PSZ;
  _Float16* xh = (_Float16*)(psG + PSZ);              // [NT][NPTS][DIM] fp16

  hipMemsetAsync(d_out, 0, sizeof(float), stream);
  init_kernel<<<(int)((PSZ + 255) / 256), 256, 0, stream>>>(x, norms, xh, pmF, psF);

  const double LN2 = 0.6931471805599453;
  const double LOGN = 7.624618986159398;  // ln(2048)
  const int NBLK = NPAIR * NGRP * NSTRIP; // 1280
  float csf = 0.f, cbf = 0.f;             // constants of the producer of Pf
  for (int t = 0; t < 80; ++t) {
    double eps = 100.0 * pow(0.95, 2.0 * (double)t);
    if (eps < 0.05) eps = 0.05;
    float kk = (float)(1.0 / (eps * LN2));
    float cs = (float)(-eps * LN2);
    float cb = (float)(eps * LOGN);
    // g-partials: rows = i (timepoint p), src = f from Pf with (csf, cbf)
    sweep_kernel<<<NBLK, 256, 0, stream>>>(xh, norms, pmF, psF, pmG, psG,
                                           0, kk, csf, cbf);
    // f-partials: rows = j (timepoint p+1), src = g from Pg with (cs, cb)
    sweep_kernel<<<NBLK, 256, 0, stream>>>(xh, norms, pmG, psG, pmF, psF,
                                           1, kk, cs, cb);
    csf = cs; cbf = cb;
  }
  out_kernel<<<NPAIR * 32, 256, 0, stream>>>(pmF, psF, pmG, psG, csf, cbf, out);
}